// Round 4
// baseline (1327.242 us; speedup 1.0000x reference)
//
#include <hip/hip_runtime.h>
#include <hip/hip_bf16.h>

typedef float f32x4 __attribute__((ext_vector_type(4)));
typedef short s16x8 __attribute__((ext_vector_type(8)));

__device__ __forceinline__ unsigned short f2bf(float f) {
    union { __hip_bfloat16 b; unsigned short u; } v;
    v.b = __float2bfloat16(f);
    return v.u;
}
__device__ __forceinline__ float sigf(float x)  { return 1.0f / (1.0f + __expf(-x)); }
__device__ __forceinline__ float siluf(float x) { return x * sigf(x); }

__device__ __forceinline__ s16x8 pack8(float4 a, float4 b) {
    s16x8 r;
    r[0]=(short)f2bf(a.x); r[1]=(short)f2bf(a.y); r[2]=(short)f2bf(a.z); r[3]=(short)f2bf(a.w);
    r[4]=(short)f2bf(b.x); r[5]=(short)f2bf(b.y); r[6]=(short)f2bf(b.z); r[7]=(short)f2bf(b.w);
    return r;
}

// ---------------------------------------------------------------------------
// Kernel 1: convert atom_fea fp32 -> bf16, rows PERMUTED into B-fragment
// split-half order: Af[a][(kh*4+q)*8 + jj] = bf16(atom[a][kh*32 + q*4 +
// (jj&3) + (jj>=4 ? 16 : 0)]).  Each lane's fragment = one 16 B load.
// ---------------------------------------------------------------------------
__global__ __launch_bounds__(256) void atom_conv_kernel(
    const float* __restrict__ atom_fea, unsigned short* __restrict__ Af, int total)
{
    int i = blockIdx.x * blockDim.x + threadIdx.x;
    const int stride = gridDim.x * blockDim.x;
    for (; i < total; i += stride) {
        int a = i >> 6, p = i & 63;
        int kh = p >> 5, q = (p >> 3) & 3, jj = p & 7;
        int k = kh * 32 + q * 4 + (jj & 3) + ((jj & 4) ? 16 : 0);
        Af[i] = f2bf(atom_fea[(size_t)a * 64 + k]);
    }
}

// ---------------------------------------------------------------------------
// Kernel 2: MFMA edge kernel, wave = 16 edges x 64 channels, persistent.
// Layer 1 swapped (W^T as A, x^T as B), full K=192 from gathered bf16 atom
// fragments + streamed e_ij. Split-half k-mapping as verified in round 3.
// ---------------------------------------------------------------------------
#define NCH 60

__global__ __launch_bounds__(512, 4) void edge_kernel(
    const unsigned short* __restrict__ Af,
    const float* __restrict__ edge_ij,
    const int*   __restrict__ nbr,
    const float* __restrict__ bonds_r,
    const float* __restrict__ W1, const float* __restrict__ b1,
    const float* __restrict__ W2, const float* __restrict__ b2,
    const float* __restrict__ W3, const float* __restrict__ b3,
    const float* __restrict__ Wr, const float* __restrict__ br,
    float* __restrict__ out, int n_edges)
{
    __shared__ unsigned short wlds[NCH * 512];   // 60 KiB weight fragments
    __shared__ float blds[128];                  // b1 | b2

    const int t    = threadIdx.x;
    const int wave = t >> 6;
    const int lane = t & 63;
    const int q    = lane >> 4;
    const int n    = lane & 15;

    // ---- stage weight fragments: chunk ch elem (l=t>>3, j=t&7):
    //      k = kh*32 + split(l>>4, j), c = nb*16 + (l&15)
    {
        const int l  = t >> 3, j = t & 7;
        const int lq = l >> 4, ln = l & 15;
        const int kk = (j < 4) ? (lq * 4 + j) : (16 + lq * 4 + (j - 4));
        for (int ch = 0; ch < NCH; ++ch) {
            float val;
            if (ch < 24) {                       // W1: kh 0..5, nb 0..3
                int kh = ch >> 2, nb = ch & 3;
                val = W1[(size_t)(kh * 32 + kk) * 64 + nb * 16 + ln];
            } else if (ch < 48) {                // W2
                int c2 = ch - 24; int kh = c2 >> 2, nb = c2 & 3;
                val = W2[(size_t)(kh * 32 + kk) * 64 + nb * 16 + ln];
            } else if (ch < 56) {                // W3: kh 0..1
                int c2 = ch - 48; int kh = c2 >> 2, nb = c2 & 3;
                val = W3[(size_t)(kh * 32 + kk) * 64 + nb * 16 + ln];
            } else {                             // Wr: K=16 zero-padded
                int nb = ch - 56;
                val = (kk < 16) ? Wr[(size_t)kk * 64 + nb * 16 + ln] : 0.0f;
            }
            wlds[ch * 512 + t] = f2bf(val);
        }
    }
    if (t < 64)       blds[t] = b1[t];
    else if (t < 128) blds[t] = b2[t - 64];
    __syncthreads();

    float b3v[4], brv[4];
    #pragma unroll
    for (int nb = 0; nb < 4; ++nb) { b3v[nb] = b3[nb * 16 + n]; brv[nb] = br[nb * 16 + n]; }

    const int tiles  = (n_edges + 15) >> 4;
    const int stride = gridDim.x * 8;
    int T = blockIdx.x * 8 + wave;
    if (T >= tiles) return;

    const int2* nb2 = (const int2*)nbr;

    // ---- prologue: indices + atom fragments for tile T, indices for T+1 ----
    int2 nbc = nb2[min(T * 16 + n, n_edges - 1)];
    s16x8 ai0 = *(const s16x8*)&Af[(size_t)nbc.x * 64 + q * 8];
    s16x8 ai1 = *(const s16x8*)&Af[(size_t)nbc.x * 64 + 32 + q * 8];
    s16x8 aj0 = *(const s16x8*)&Af[(size_t)nbc.y * 64 + q * 8];
    s16x8 aj1 = *(const s16x8*)&Af[(size_t)nbc.y * 64 + 32 + q * 8];
    int Tn = T + stride;
    int2 nbn = nbc;
    if (Tn < tiles) nbn = nb2[min(Tn * 16 + n, n_edges - 1)];

    while (true) {
        const int E0 = T * 16;
        const int e  = min(E0 + n, n_edges - 1);

        // ---- stream loads for this tile (e_ij + bonds) ----
        const float* xr = edge_ij + (size_t)e * 64;
        float4 x00 = *(const float4*)(xr +      q * 4);
        float4 x01 = *(const float4*)(xr + 16 + q * 4);
        float4 x10 = *(const float4*)(xr + 32 + q * 4);
        float4 x11 = *(const float4*)(xr + 48 + q * 4);
        float4 bl  = *(const float4*)(bonds_r + (size_t)e * 16 + q * 4);

        // ---- acc init = biases (C layout row = ch = nb*16+q*4+j) ----
        f32x4 acc1[4], acc2[4];
        #pragma unroll
        for (int nb = 0; nb < 4; ++nb) {
            acc1[nb] = *(const f32x4*)&blds[nb * 16 + q * 4];
            acc2[nb] = *(const f32x4*)&blds[64 + nb * 16 + q * 4];
        }

        // ---- layer 1, atom part: kh 0..3 (B-frags ai0,ai1,aj0,aj1) ----
        #pragma unroll
        for (int nb = 0; nb < 4; ++nb) {
            s16x8 w;
            w = *(const s16x8*)&wlds[( 0 + nb) * 512 + lane * 8];
            acc1[nb] = __builtin_amdgcn_mfma_f32_16x16x32_bf16(w, ai0, acc1[nb], 0, 0, 0);
            w = *(const s16x8*)&wlds[( 4 + nb) * 512 + lane * 8];
            acc1[nb] = __builtin_amdgcn_mfma_f32_16x16x32_bf16(w, ai1, acc1[nb], 0, 0, 0);
            w = *(const s16x8*)&wlds[( 8 + nb) * 512 + lane * 8];
            acc1[nb] = __builtin_amdgcn_mfma_f32_16x16x32_bf16(w, aj0, acc1[nb], 0, 0, 0);
            w = *(const s16x8*)&wlds[(12 + nb) * 512 + lane * 8];
            acc1[nb] = __builtin_amdgcn_mfma_f32_16x16x32_bf16(w, aj1, acc1[nb], 0, 0, 0);
            w = *(const s16x8*)&wlds[(24 + nb) * 512 + lane * 8];
            acc2[nb] = __builtin_amdgcn_mfma_f32_16x16x32_bf16(w, ai0, acc2[nb], 0, 0, 0);
            w = *(const s16x8*)&wlds[(28 + nb) * 512 + lane * 8];
            acc2[nb] = __builtin_amdgcn_mfma_f32_16x16x32_bf16(w, ai1, acc2[nb], 0, 0, 0);
            w = *(const s16x8*)&wlds[(32 + nb) * 512 + lane * 8];
            acc2[nb] = __builtin_amdgcn_mfma_f32_16x16x32_bf16(w, aj0, acc2[nb], 0, 0, 0);
            w = *(const s16x8*)&wlds[(36 + nb) * 512 + lane * 8];
            acc2[nb] = __builtin_amdgcn_mfma_f32_16x16x32_bf16(w, aj1, acc2[nb], 0, 0, 0);
        }

        // ---- atom frags dead: prefetch next tile's (latency hidden below) ----
        const bool havenext = (Tn < tiles);
        if (havenext) {
            ai0 = *(const s16x8*)&Af[(size_t)nbn.x * 64 + q * 8];
            ai1 = *(const s16x8*)&Af[(size_t)nbn.x * 64 + 32 + q * 8];
            aj0 = *(const s16x8*)&Af[(size_t)nbn.y * 64 + q * 8];
            aj1 = *(const s16x8*)&Af[(size_t)nbn.y * 64 + 32 + q * 8];
            int T2 = Tn + stride;
            if (T2 < tiles) nbn = nb2[min(T2 * 16 + n, n_edges - 1)];
        }

        // ---- layer 1, e_ij part: kh 4..5 ----
        s16x8 xf0 = pack8(x00, x01);
        s16x8 xf1 = pack8(x10, x11);
        #pragma unroll
        for (int nb = 0; nb < 4; ++nb) {
            s16x8 w;
            w = *(const s16x8*)&wlds[(16 + nb) * 512 + lane * 8];
            acc1[nb] = __builtin_amdgcn_mfma_f32_16x16x32_bf16(w, xf0, acc1[nb], 0, 0, 0);
            w = *(const s16x8*)&wlds[(20 + nb) * 512 + lane * 8];
            acc1[nb] = __builtin_amdgcn_mfma_f32_16x16x32_bf16(w, xf1, acc1[nb], 0, 0, 0);
            w = *(const s16x8*)&wlds[(40 + nb) * 512 + lane * 8];
            acc2[nb] = __builtin_amdgcn_mfma_f32_16x16x32_bf16(w, xf0, acc2[nb], 0, 0, 0);
            w = *(const s16x8*)&wlds[(44 + nb) * 512 + lane * 8];
            acc2[nb] = __builtin_amdgcn_mfma_f32_16x16x32_bf16(w, xf1, acc2[nb], 0, 0, 0);
        }

        // ---- h lane-local: lane(q,n) holds h[ch=nb*16+q*4+j][edge n] ----
        s16x8 hf0, hf1;
        #pragma unroll
        for (int j = 0; j < 4; ++j) {
            hf0[j]     = (short)f2bf(siluf(acc1[0][j]) * sigf(acc2[0][j]));
            hf0[4 + j] = (short)f2bf(siluf(acc1[1][j]) * sigf(acc2[1][j]));
            hf1[j]     = (short)f2bf(siluf(acc1[2][j]) * sigf(acc2[2][j]));
            hf1[4 + j] = (short)f2bf(siluf(acc1[3][j]) * sigf(acc2[3][j]));
        }

        // ---- layer 2 (h @ W3) and gate (bonds @ Wr), normal orientation ----
        s16x8 bfrag = pack8(bl, make_float4(0.f, 0.f, 0.f, 0.f));
        f32x4 a3[4], g[4];
        #pragma unroll
        for (int nb = 0; nb < 4; ++nb) { a3[nb] = (f32x4){0,0,0,0}; g[nb] = (f32x4){0,0,0,0}; }
        #pragma unroll
        for (int nb = 0; nb < 4; ++nb) {
            s16x8 w3a = *(const s16x8*)&wlds[(48 + nb) * 512 + lane * 8];
            a3[nb] = __builtin_amdgcn_mfma_f32_16x16x32_bf16(hf0, w3a, a3[nb], 0, 0, 0);
            s16x8 w3b = *(const s16x8*)&wlds[(52 + nb) * 512 + lane * 8];
            a3[nb] = __builtin_amdgcn_mfma_f32_16x16x32_bf16(hf1, w3b, a3[nb], 0, 0, 0);
            s16x8 wr  = *(const s16x8*)&wlds[(56 + nb) * 512 + lane * 8];
            g[nb]  = __builtin_amdgcn_mfma_f32_16x16x32_bf16(bfrag, wr, g[nb], 0, 0, 0);
        }

        // ---- out[edge q*4+j][oc nb*16+n] = silu(a3+b3)*(g+br) ----
        #pragma unroll
        for (int nb = 0; nb < 4; ++nb) {
            #pragma unroll
            for (int j = 0; j < 4; ++j) {
                int grow = E0 + q * 4 + j;
                if (grow < n_edges) {
                    out[(size_t)grow * 64 + nb * 16 + n] =
                        siluf(a3[nb][j] + b3v[nb]) * (g[nb][j] + brv[nb]);
                }
            }
        }

        if (!havenext) break;
        T = Tn;
        Tn = T + stride;
    }
}

// ---------------------------------------------------------------------------
extern "C" void kernel_launch(void* const* d_in, const int* in_sizes, int n_in,
                              void* d_out, int out_size, void* d_ws, size_t ws_size,
                              hipStream_t stream) {
    const float* atom_fea = (const float*)d_in[0];
    const float* edge_ij  = (const float*)d_in[1];
    const int*   nbr      = (const int*)  d_in[2];
    const float* bonds_r  = (const float*)d_in[3];
    const float* W1 = (const float*)d_in[4];
    const float* b1 = (const float*)d_in[5];
    const float* W2 = (const float*)d_in[6];
    const float* b2 = (const float*)d_in[7];
    const float* Wr = (const float*)d_in[8];
    const float* br = (const float*)d_in[9];
    const float* W3 = (const float*)d_in[10];
    const float* b3 = (const float*)d_in[11];
    float* out = (float*)d_out;
    unsigned short* Af = (unsigned short*)d_ws;   // 50000*64 bf16 = 6.4 MB

    const int n_atoms = in_sizes[0] / 64;
    const int n_edges = in_sizes[2] / 2;

    hipLaunchKernelGGL(atom_conv_kernel, dim3(2048), dim3(256), 0, stream,
                       atom_fea, Af, n_atoms * 64);

    hipLaunchKernelGGL(edge_kernel, dim3(512), dim3(512), 0, stream,
                       Af, edge_ij, nbr, bonds_r,
                       W1, b1, W2, b2, W3, b3, Wr, br, out, n_edges);
}

// Round 5
// 766.287 us; speedup vs baseline: 1.7320x; 1.7320x over previous
//
#include <hip/hip_runtime.h>
#include <hip/hip_bf16.h>

typedef float f32x4 __attribute__((ext_vector_type(4)));
typedef short s16x8 __attribute__((ext_vector_type(8)));

__device__ __forceinline__ unsigned short f2bf(float f) {
    union { __hip_bfloat16 b; unsigned short u; } v;
    v.b = __float2bfloat16(f);
    return v.u;
}
__device__ __forceinline__ float sigf(float x)  { return 1.0f / (1.0f + __expf(-x)); }
__device__ __forceinline__ float siluf(float x) { return x * sigf(x); }

__device__ __forceinline__ s16x8 pack8(float4 a, float4 b) {
    s16x8 r;
    r[0]=(short)f2bf(a.x); r[1]=(short)f2bf(a.y); r[2]=(short)f2bf(a.z); r[3]=(short)f2bf(a.w);
    r[4]=(short)f2bf(b.x); r[5]=(short)f2bf(b.y); r[6]=(short)f2bf(b.z); r[7]=(short)f2bf(b.w);
    return r;
}

// ---------------------------------------------------------------------------
// Kernel 1: convert atom_fea fp32 -> bf16, rows PERMUTED into B-fragment
// split-half order: Af[a][(kh*4+q)*8 + jj] = bf16(atom[a][kh*32 + q*4 +
// (jj&3) + (jj>=4 ? 16 : 0)]).  Each lane's fragment = one 16 B load.
// ---------------------------------------------------------------------------
__global__ __launch_bounds__(256) void atom_conv_kernel(
    const float* __restrict__ atom_fea, unsigned short* __restrict__ Af, int total)
{
    int i = blockIdx.x * blockDim.x + threadIdx.x;
    const int stride = gridDim.x * blockDim.x;
    for (; i < total; i += stride) {
        int a = i >> 6, p = i & 63;
        int kh = p >> 5, q = (p >> 3) & 3, jj = p & 7;
        int k = kh * 32 + q * 4 + (jj & 3) + ((jj & 4) ? 16 : 0);
        Af[i] = f2bf(atom_fea[(size_t)a * 64 + k]);
    }
}

// ---------------------------------------------------------------------------
// Kernel 2: MFMA edge kernel, wave = 16 edges x 64 channels, persistent.
// Layer 1 swapped (W^T as A, x^T as B), full K=192 from gathered bf16 atom
// fragments + streamed e_ij. Split-half k-mapping as verified in round 3.
// __launch_bounds__(512, 2): VGPR cap 256 — round 4's (512,4) forced 64 VGPR
// and spilled (+247 MB scratch writes). LDS 61 KB -> 2 blocks/CU at runtime.
// ---------------------------------------------------------------------------
#define NCH 60

__global__ __launch_bounds__(512, 2) void edge_kernel(
    const unsigned short* __restrict__ Af,
    const float* __restrict__ edge_ij,
    const int*   __restrict__ nbr,
    const float* __restrict__ bonds_r,
    const float* __restrict__ W1, const float* __restrict__ b1,
    const float* __restrict__ W2, const float* __restrict__ b2,
    const float* __restrict__ W3, const float* __restrict__ b3,
    const float* __restrict__ Wr, const float* __restrict__ br,
    float* __restrict__ out, int n_edges)
{
    __shared__ unsigned short wlds[NCH * 512];   // 60 KiB weight fragments
    __shared__ float blds[128];                  // b1 | b2

    const int t    = threadIdx.x;
    const int wave = t >> 6;
    const int lane = t & 63;
    const int q    = lane >> 4;
    const int n    = lane & 15;

    // ---- stage weight fragments: chunk ch elem (l=t>>3, j=t&7):
    //      k = kh*32 + split(l>>4, j), c = nb*16 + (l&15)
    {
        const int l  = t >> 3, j = t & 7;
        const int lq = l >> 4, ln = l & 15;
        const int kk = (j < 4) ? (lq * 4 + j) : (16 + lq * 4 + (j - 4));
        for (int ch = 0; ch < NCH; ++ch) {
            float val;
            if (ch < 24) {                       // W1: kh 0..5, nb 0..3
                int kh = ch >> 2, nb = ch & 3;
                val = W1[(size_t)(kh * 32 + kk) * 64 + nb * 16 + ln];
            } else if (ch < 48) {                // W2
                int c2 = ch - 24; int kh = c2 >> 2, nb = c2 & 3;
                val = W2[(size_t)(kh * 32 + kk) * 64 + nb * 16 + ln];
            } else if (ch < 56) {                // W3: kh 0..1
                int c2 = ch - 48; int kh = c2 >> 2, nb = c2 & 3;
                val = W3[(size_t)(kh * 32 + kk) * 64 + nb * 16 + ln];
            } else {                             // Wr: K=16 zero-padded
                int nb = ch - 56;
                val = (kk < 16) ? Wr[(size_t)kk * 64 + nb * 16 + ln] : 0.0f;
            }
            wlds[ch * 512 + t] = f2bf(val);
        }
    }
    if (t < 64)       blds[t] = b1[t];
    else if (t < 128) blds[t] = b2[t - 64];
    __syncthreads();

    float b3v[4], brv[4];
    #pragma unroll
    for (int nb = 0; nb < 4; ++nb) { b3v[nb] = b3[nb * 16 + n]; brv[nb] = br[nb * 16 + n]; }

    const int tiles  = (n_edges + 15) >> 4;
    const int stride = gridDim.x * 8;
    int T = blockIdx.x * 8 + wave;
    if (T >= tiles) return;

    const int2* nb2 = (const int2*)nbr;

    // ---- prologue: indices + atom fragments for tile T, indices for T+1 ----
    int2 nbc = nb2[min(T * 16 + n, n_edges - 1)];
    s16x8 ai0 = *(const s16x8*)&Af[(size_t)nbc.x * 64 + q * 8];
    s16x8 ai1 = *(const s16x8*)&Af[(size_t)nbc.x * 64 + 32 + q * 8];
    s16x8 aj0 = *(const s16x8*)&Af[(size_t)nbc.y * 64 + q * 8];
    s16x8 aj1 = *(const s16x8*)&Af[(size_t)nbc.y * 64 + 32 + q * 8];
    int Tn = T + stride;
    int2 nbn = nbc;
    if (Tn < tiles) nbn = nb2[min(Tn * 16 + n, n_edges - 1)];

    while (true) {
        const int E0 = T * 16;
        const int e  = min(E0 + n, n_edges - 1);

        // ---- stream loads for this tile; pack to bf16 immediately so the
        //      raw fp32 values don't stay live across the MFMA sections ----
        const float* xr = edge_ij + (size_t)e * 64;
        s16x8 xf0 = pack8(*(const float4*)(xr +      q * 4),
                          *(const float4*)(xr + 16 + q * 4));
        s16x8 xf1 = pack8(*(const float4*)(xr + 32 + q * 4),
                          *(const float4*)(xr + 48 + q * 4));
        s16x8 bfrag = pack8(*(const float4*)(bonds_r + (size_t)e * 16 + q * 4),
                            make_float4(0.f, 0.f, 0.f, 0.f));

        // ---- acc init = biases (C layout row = ch = nb*16+q*4+j) ----
        f32x4 acc1[4], acc2[4];
        #pragma unroll
        for (int nb = 0; nb < 4; ++nb) {
            acc1[nb] = *(const f32x4*)&blds[nb * 16 + q * 4];
            acc2[nb] = *(const f32x4*)&blds[64 + nb * 16 + q * 4];
        }

        // ---- layer 1, atom part: kh 0..3 (B-frags ai0,ai1,aj0,aj1) ----
        #pragma unroll
        for (int nb = 0; nb < 4; ++nb) {
            s16x8 w;
            w = *(const s16x8*)&wlds[( 0 + nb) * 512 + lane * 8];
            acc1[nb] = __builtin_amdgcn_mfma_f32_16x16x32_bf16(w, ai0, acc1[nb], 0, 0, 0);
            w = *(const s16x8*)&wlds[( 4 + nb) * 512 + lane * 8];
            acc1[nb] = __builtin_amdgcn_mfma_f32_16x16x32_bf16(w, ai1, acc1[nb], 0, 0, 0);
            w = *(const s16x8*)&wlds[( 8 + nb) * 512 + lane * 8];
            acc1[nb] = __builtin_amdgcn_mfma_f32_16x16x32_bf16(w, aj0, acc1[nb], 0, 0, 0);
            w = *(const s16x8*)&wlds[(12 + nb) * 512 + lane * 8];
            acc1[nb] = __builtin_amdgcn_mfma_f32_16x16x32_bf16(w, aj1, acc1[nb], 0, 0, 0);
            w = *(const s16x8*)&wlds[(24 + nb) * 512 + lane * 8];
            acc2[nb] = __builtin_amdgcn_mfma_f32_16x16x32_bf16(w, ai0, acc2[nb], 0, 0, 0);
            w = *(const s16x8*)&wlds[(28 + nb) * 512 + lane * 8];
            acc2[nb] = __builtin_amdgcn_mfma_f32_16x16x32_bf16(w, ai1, acc2[nb], 0, 0, 0);
            w = *(const s16x8*)&wlds[(32 + nb) * 512 + lane * 8];
            acc2[nb] = __builtin_amdgcn_mfma_f32_16x16x32_bf16(w, aj0, acc2[nb], 0, 0, 0);
            w = *(const s16x8*)&wlds[(36 + nb) * 512 + lane * 8];
            acc2[nb] = __builtin_amdgcn_mfma_f32_16x16x32_bf16(w, aj1, acc2[nb], 0, 0, 0);
        }

        // ---- atom frags dead: prefetch next tile's (latency hidden below) ----
        const bool havenext = (Tn < tiles);
        if (havenext) {
            ai0 = *(const s16x8*)&Af[(size_t)nbn.x * 64 + q * 8];
            ai1 = *(const s16x8*)&Af[(size_t)nbn.x * 64 + 32 + q * 8];
            aj0 = *(const s16x8*)&Af[(size_t)nbn.y * 64 + q * 8];
            aj1 = *(const s16x8*)&Af[(size_t)nbn.y * 64 + 32 + q * 8];
            int T2 = Tn + stride;
            if (T2 < tiles) nbn = nb2[min(T2 * 16 + n, n_edges - 1)];
        }

        // ---- layer 1, e_ij part: kh 4..5 ----
        #pragma unroll
        for (int nb = 0; nb < 4; ++nb) {
            s16x8 w;
            w = *(const s16x8*)&wlds[(16 + nb) * 512 + lane * 8];
            acc1[nb] = __builtin_amdgcn_mfma_f32_16x16x32_bf16(w, xf0, acc1[nb], 0, 0, 0);
            w = *(const s16x8*)&wlds[(20 + nb) * 512 + lane * 8];
            acc1[nb] = __builtin_amdgcn_mfma_f32_16x16x32_bf16(w, xf1, acc1[nb], 0, 0, 0);
            w = *(const s16x8*)&wlds[(40 + nb) * 512 + lane * 8];
            acc2[nb] = __builtin_amdgcn_mfma_f32_16x16x32_bf16(w, xf0, acc2[nb], 0, 0, 0);
            w = *(const s16x8*)&wlds[(44 + nb) * 512 + lane * 8];
            acc2[nb] = __builtin_amdgcn_mfma_f32_16x16x32_bf16(w, xf1, acc2[nb], 0, 0, 0);
        }

        // ---- h lane-local: lane(q,n) holds h[ch=nb*16+q*4+j][edge n] ----
        s16x8 hf0, hf1;
        #pragma unroll
        for (int j = 0; j < 4; ++j) {
            hf0[j]     = (short)f2bf(siluf(acc1[0][j]) * sigf(acc2[0][j]));
            hf0[4 + j] = (short)f2bf(siluf(acc1[1][j]) * sigf(acc2[1][j]));
            hf1[j]     = (short)f2bf(siluf(acc1[2][j]) * sigf(acc2[2][j]));
            hf1[4 + j] = (short)f2bf(siluf(acc1[3][j]) * sigf(acc2[3][j]));
        }

        // ---- layer 2 (h @ W3) and gate (bonds @ Wr), normal orientation ----
        f32x4 a3[4], g[4];
        #pragma unroll
        for (int nb = 0; nb < 4; ++nb) { a3[nb] = (f32x4){0,0,0,0}; g[nb] = (f32x4){0,0,0,0}; }
        #pragma unroll
        for (int nb = 0; nb < 4; ++nb) {
            s16x8 w3a = *(const s16x8*)&wlds[(48 + nb) * 512 + lane * 8];
            a3[nb] = __builtin_amdgcn_mfma_f32_16x16x32_bf16(hf0, w3a, a3[nb], 0, 0, 0);
            s16x8 w3b = *(const s16x8*)&wlds[(52 + nb) * 512 + lane * 8];
            a3[nb] = __builtin_amdgcn_mfma_f32_16x16x32_bf16(hf1, w3b, a3[nb], 0, 0, 0);
            s16x8 wr  = *(const s16x8*)&wlds[(56 + nb) * 512 + lane * 8];
            g[nb]  = __builtin_amdgcn_mfma_f32_16x16x32_bf16(bfrag, wr, g[nb], 0, 0, 0);
        }

        // ---- out[edge q*4+j][oc nb*16+n] = silu(a3+b3)*(g+br) ----
        #pragma unroll
        for (int nb = 0; nb < 4; ++nb) {
            #pragma unroll
            for (int j = 0; j < 4; ++j) {
                int grow = E0 + q * 4 + j;
                if (grow < n_edges) {
                    out[(size_t)grow * 64 + nb * 16 + n] =
                        siluf(a3[nb][j] + b3v[nb]) * (g[nb][j] + brv[nb]);
                }
            }
        }

        if (!havenext) break;
        T = Tn;
        Tn = T + stride;
    }
}

// ---------------------------------------------------------------------------
extern "C" void kernel_launch(void* const* d_in, const int* in_sizes, int n_in,
                              void* d_out, int out_size, void* d_ws, size_t ws_size,
                              hipStream_t stream) {
    const float* atom_fea = (const float*)d_in[0];
    const float* edge_ij  = (const float*)d_in[1];
    const int*   nbr      = (const int*)  d_in[2];
    const float* bonds_r  = (const float*)d_in[3];
    const float* W1 = (const float*)d_in[4];
    const float* b1 = (const float*)d_in[5];
    const float* W2 = (const float*)d_in[6];
    const float* b2 = (const float*)d_in[7];
    const float* Wr = (const float*)d_in[8];
    const float* br = (const float*)d_in[9];
    const float* W3 = (const float*)d_in[10];
    const float* b3 = (const float*)d_in[11];
    float* out = (float*)d_out;
    unsigned short* Af = (unsigned short*)d_ws;   // 50000*64 bf16 = 6.4 MB

    const int n_atoms = in_sizes[0] / 64;
    const int n_edges = in_sizes[2] / 2;

    hipLaunchKernelGGL(atom_conv_kernel, dim3(2048), dim3(256), 0, stream,
                       atom_fea, Af, n_atoms * 64);

    hipLaunchKernelGGL(edge_kernel, dim3(512), dim3(512), 0, stream,
                       Af, edge_ij, nbr, bonds_r,
                       W1, b1, W2, b2, W3, b3, Wr, br, out, n_edges);
}